// Round 1
// baseline (1128.965 us; speedup 1.0000x reference)
//
#include <hip/hip_runtime.h>

// EquivariantConvolution: fused per-edge kernel, f32 vector compute.
// Shapes: E=262144, N=65536, EDGE_DIM=16, HIDDEN=32, M1=M2=8, D1=D2=4, K1=K2=4.
// d_in: 0=basis1(E,4,4) 1=basis2(E,4,4) 2=edge_feats(E,16) 3=f(N,8,4)
//       4=src_idx(E) 5=w1(16,32) 6=bias1(32) 7=w2(32,1024) 8=bias2(1024)
// out: (E,8,4) f32.

#define TPB 256

__global__ __launch_bounds__(TPB, 2) void equiv_conv_kernel(
    const float* __restrict__ basis1,
    const float* __restrict__ basis2,
    const float* __restrict__ ef,
    const float* __restrict__ f,
    const int*   __restrict__ src_idx,
    const float* __restrict__ w1,
    const float* __restrict__ b1,
    const float* __restrict__ w2,
    const float* __restrict__ b2,
    float* __restrict__ out)
{
    // h staged transposed [j][tid]: main-loop read lds_h[j][tid] is
    // consecutive-address across lanes -> conflict-free.
    __shared__ float lds_h[32][TPB];

    const int tid = threadIdx.x;
    const int e   = blockIdx.x * TPB + tid;   // grid sized exactly E/TPB

    // ---- load edge features (16 f32, 64B contiguous per thread) ----
    float efr[16];
    {
        const float4* p4 = reinterpret_cast<const float4*>(ef + e * 16);
        #pragma unroll
        for (int i = 0; i < 4; ++i) {
            float4 v = p4[i];
            efr[i*4+0] = v.x; efr[i*4+1] = v.y; efr[i*4+2] = v.z; efr[i*4+3] = v.w;
        }
    }

    // ---- h = relu(ef @ w1 + b1); store to LDS (w1/b1 via uniform s_loads) ----
    #pragma unroll
    for (int j = 0; j < 32; ++j) {
        float hv = b1[j];
        #pragma unroll
        for (int i = 0; i < 16; ++i)
            hv = fmaf(efr[i], w1[i*32 + j], hv);
        lds_h[j][tid] = fmaxf(hv, 0.f);
    }

    // ---- gather f_src (32 f32) and basis1 (16 f32); tmp[m*4+k] ----
    float fr[32];
    {
        const int s = src_idx[e];
        const float4* p4 = reinterpret_cast<const float4*>(f + s * 32);
        #pragma unroll
        for (int i = 0; i < 8; ++i) {
            float4 v = p4[i];
            fr[i*4+0] = v.x; fr[i*4+1] = v.y; fr[i*4+2] = v.z; fr[i*4+3] = v.w;
        }
    }
    float bs1[16];
    {
        const float4* p4 = reinterpret_cast<const float4*>(basis1 + e * 16);
        #pragma unroll
        for (int i = 0; i < 4; ++i) {
            float4 v = p4[i];
            bs1[i*4+0] = v.x; bs1[i*4+1] = v.y; bs1[i*4+2] = v.z; bs1[i*4+3] = v.w;
        }
    }
    float tmp[32];
    #pragma unroll
    for (int m = 0; m < 8; ++m) {
        #pragma unroll
        for (int k = 0; k < 4; ++k) {
            float v = 0.f;
            #pragma unroll
            for (int d = 0; d < 4; ++d)
                v = fmaf(fr[m*4+d], bs1[d*4+k], v);
            tmp[m*4+k] = v;
        }
    }

    // ---- acc[a] = bias2[a,:] . tmp  (bias2 uniform s_loads; zeros in data
    //      but implemented for correctness) ----
    float acc[32];
    #pragma unroll
    for (int a = 0; a < 32; ++a) {
        float v = 0.f;
        #pragma unroll
        for (int b = 0; b < 32; ++b)
            v = fmaf(tmp[b], b2[a*32 + b], v);
        acc[a] = v;
    }

    __syncthreads();

    // ---- main contraction: acc[a] += sum_j h[j] * (w2[j,a,:] . tmp) ----
    // w2 index depends only on loop counters -> wave-uniform -> scalar loads.
    #pragma unroll 1
    for (int j = 0; j < 32; ++j) {
        const float hj = lds_h[j][tid];
        float p[32];
        #pragma unroll
        for (int b = 0; b < 32; ++b)
            p[b] = hj * tmp[b];
        const float* wrow = w2 + j * 1024;
        #pragma unroll
        for (int a = 0; a < 32; ++a) {
            float v = acc[a];
            #pragma unroll
            for (int b = 0; b < 32; ++b)
                v = fmaf(p[b], wrow[a*32 + b], v);
            acc[a] = v;
        }
    }

    // ---- epilogue: out[m2,d2] = sum_k2 acc[m2*4+k2] * basis2[k2,d2] ----
    float bs2[16];
    {
        const float4* p4 = reinterpret_cast<const float4*>(basis2 + e * 16);
        #pragma unroll
        for (int i = 0; i < 4; ++i) {
            float4 v = p4[i];
            bs2[i*4+0] = v.x; bs2[i*4+1] = v.y; bs2[i*4+2] = v.z; bs2[i*4+3] = v.w;
        }
    }
    float* op = out + e * 32;
    #pragma unroll
    for (int m = 0; m < 8; ++m) {
        float4 v;
        v.x = fmaf(acc[m*4+0], bs2[0*4+0], fmaf(acc[m*4+1], bs2[1*4+0],
              fmaf(acc[m*4+2], bs2[2*4+0], acc[m*4+3] * bs2[3*4+0])));
        v.y = fmaf(acc[m*4+0], bs2[0*4+1], fmaf(acc[m*4+1], bs2[1*4+1],
              fmaf(acc[m*4+2], bs2[2*4+1], acc[m*4+3] * bs2[3*4+1])));
        v.z = fmaf(acc[m*4+0], bs2[0*4+2], fmaf(acc[m*4+1], bs2[1*4+2],
              fmaf(acc[m*4+2], bs2[2*4+2], acc[m*4+3] * bs2[3*4+2])));
        v.w = fmaf(acc[m*4+0], bs2[0*4+3], fmaf(acc[m*4+1], bs2[1*4+3],
              fmaf(acc[m*4+2], bs2[2*4+3], acc[m*4+3] * bs2[3*4+3])));
        reinterpret_cast<float4*>(op)[m] = v;
    }
}

extern "C" void kernel_launch(void* const* d_in, const int* in_sizes, int n_in,
                              void* d_out, int out_size, void* d_ws, size_t ws_size,
                              hipStream_t stream) {
    const float* basis1 = (const float*)d_in[0];
    const float* basis2 = (const float*)d_in[1];
    const float* ef     = (const float*)d_in[2];
    const float* f      = (const float*)d_in[3];
    const int*   src    = (const int*)  d_in[4];
    const float* w1     = (const float*)d_in[5];
    const float* b1     = (const float*)d_in[6];
    const float* w2     = (const float*)d_in[7];
    const float* b2     = (const float*)d_in[8];
    float* out = (float*)d_out;

    const int E = in_sizes[4];            // 262144
    const int nblocks = E / TPB;          // 1024

    equiv_conv_kernel<<<nblocks, TPB, 0, stream>>>(
        basis1, basis2, ef, f, src, w1, b1, w2, b2, out);
}

// Round 2
// 63.651 us; speedup vs baseline: 17.7369x; 17.7369x over previous
//
#include <hip/hip_runtime.h>
#include <hip/hip_bf16.h>

// EquivariantConvolution via bf16 MFMA.
// GEMM view: C[e,a] = sum_{j,b} (h[e,j]*tmp[e,b]) * w2[j, a*32+b],  K=j*32+b=1024, N=32.
// Within one K=32 MFMA step, j == kk is constant -> A-frag = h[e,kk] * tmp[e, b].
// bias2 folded in as one extra K-step with implicit h == 1.
// Epilogue out[e,m2,d2] = sum_k2 C[e, m2*4+k2] * basis2[e,k2,d2] in C-fragment layout.

#define TPB 256
#define BM  256

typedef __attribute__((ext_vector_type(8))) short bf16x8;
typedef __attribute__((ext_vector_type(4))) float f32x4;

__device__ __forceinline__ ushort f2bf(float x) {
    __hip_bfloat16 b = __float2bfloat16(x);
    return __builtin_bit_cast(ushort, b);
}
__device__ __forceinline__ float bf2f(ushort u) {
    unsigned int v = ((unsigned int)u) << 16;
    return __builtin_bit_cast(float, v);
}

__global__ __launch_bounds__(TPB, 2) void equiv_conv_mfma(
    const float* __restrict__ basis1,
    const float* __restrict__ basis2,
    const float* __restrict__ ef,
    const float* __restrict__ f,
    const int*   __restrict__ src_idx,
    const float* __restrict__ w1,
    const float* __restrict__ b1,
    const float* __restrict__ w2,
    const float* __restrict__ b2,
    float* __restrict__ out)
{
    // LDS: 16 KB + 16 KB + 32 KB = 64 KB -> 2 blocks/CU.
    __shared__ ushort hT[32 * BM];        // [j][edge]  bf16 bits
    __shared__ ushort tmpT[4 * BM * 8];   // [g][edge][8] bf16 (b = g*8+i)
    __shared__ ushort WL[2 * 8192];       // [buf][jr][g][a][i] bf16 (8 rows/chunk)

    const int tid  = threadIdx.x;
    const int base = blockIdx.x * BM;
    const int e    = base + tid;

    const int jr = tid >> 5;      // row-in-chunk this thread stages
    const int tt = tid & 31;

    // ---- T14: issue chunk-0 w2 loads early (land under prologue compute) ----
    f32x4 stg[8];
    {
        const float* p = w2 + jr * 1024 + tt * 4;
        #pragma unroll
        for (int i = 0; i < 8; ++i)
            stg[i] = *reinterpret_cast<const f32x4*>(p + i * 128);
    }

    // lambda: write staged regs (bf16) into WL[dbuf]; works for bias row too (jr==0).
    auto write_stage = [&](int dbuf) {
        const int g   = (tt >> 1) & 3;
        const int i0v = (tt & 1) * 4;
        #pragma unroll
        for (int i = 0; i < 8; ++i) {
            const int a = i * 4 + (tt >> 3);
            unsigned int lo = (unsigned int)f2bf(stg[i][0]) | ((unsigned int)f2bf(stg[i][1]) << 16);
            unsigned int hi = (unsigned int)f2bf(stg[i][2]) | ((unsigned int)f2bf(stg[i][3]) << 16);
            *reinterpret_cast<uint2*>(&WL[dbuf * 8192 + jr * 1024 + g * 256 + a * 8 + i0v]) =
                make_uint2(lo, hi);
        }
    };

    // ---- prologue: h = relu(ef@w1 + b1) -> hT (bf16) ----
    {
        float efr[16];
        const f32x4* p4 = reinterpret_cast<const f32x4*>(ef + e * 16);
        #pragma unroll
        for (int i = 0; i < 4; ++i) {
            f32x4 v = p4[i];
            efr[i*4+0] = v[0]; efr[i*4+1] = v[1]; efr[i*4+2] = v[2]; efr[i*4+3] = v[3];
        }
        #pragma unroll
        for (int j = 0; j < 32; ++j) {
            float hv = b1[j];
            #pragma unroll
            for (int i = 0; i < 16; ++i)
                hv = fmaf(efr[i], w1[i * 32 + j], hv);
            hT[j * BM + tid] = f2bf(fmaxf(hv, 0.f));
        }
    }

    // ---- prologue: tmp[m*4+k] = sum_d f_src[m][d]*basis1[d][k] -> tmpT (bf16) ----
    {
        float fr[32];
        const int s = src_idx[e];
        const f32x4* p4 = reinterpret_cast<const f32x4*>(f + s * 32);
        #pragma unroll
        for (int i = 0; i < 8; ++i) {
            f32x4 v = p4[i];
            fr[i*4+0] = v[0]; fr[i*4+1] = v[1]; fr[i*4+2] = v[2]; fr[i*4+3] = v[3];
        }
        float bs1[16];
        const f32x4* q4 = reinterpret_cast<const f32x4*>(basis1 + e * 16);
        #pragma unroll
        for (int i = 0; i < 4; ++i) {
            f32x4 v = q4[i];
            bs1[i*4+0] = v[0]; bs1[i*4+1] = v[1]; bs1[i*4+2] = v[2]; bs1[i*4+3] = v[3];
        }
        float tmp[32];
        #pragma unroll
        for (int m = 0; m < 8; ++m) {
            #pragma unroll
            for (int k = 0; k < 4; ++k) {
                float v = 0.f;
                #pragma unroll
                for (int d = 0; d < 4; ++d)
                    v = fmaf(fr[m*4+d], bs1[d*4+k], v);
                tmp[m*4+k] = v;
            }
        }
        #pragma unroll
        for (int g = 0; g < 4; ++g) {
            uint4 pk;
            pk.x = (unsigned int)f2bf(tmp[g*8+0]) | ((unsigned int)f2bf(tmp[g*8+1]) << 16);
            pk.y = (unsigned int)f2bf(tmp[g*8+2]) | ((unsigned int)f2bf(tmp[g*8+3]) << 16);
            pk.z = (unsigned int)f2bf(tmp[g*8+4]) | ((unsigned int)f2bf(tmp[g*8+5]) << 16);
            pk.w = (unsigned int)f2bf(tmp[g*8+6]) | ((unsigned int)f2bf(tmp[g*8+7]) << 16);
            *reinterpret_cast<uint4*>(&tmpT[(g * BM + tid) * 8]) = pk;
        }
    }

    // chunk 0 -> WL[0]
    write_stage(0);
    __syncthreads();

    // ---- per-wave tile setup ----
    const int lane = tid & 63;
    const int wid  = tid >> 6;
    const int l15  = lane & 15;
    const int lg   = lane >> 4;            // K-group (b = lg*8 + i)

    float tmpf[4][8];                      // per-tile tmp[b] as f32, K-loop invariant
    #pragma unroll
    for (int q = 0; q < 4; ++q) {
        const int edge = wid * 64 + q * 16 + l15;
        bf16x8 tv = *reinterpret_cast<const bf16x8*>(&tmpT[(lg * BM + edge) * 8]);
        #pragma unroll
        for (int i = 0; i < 8; ++i) tmpf[q][i] = bf2f((ushort)tv[i]);
    }

    f32x4 acc[4][2];
    #pragma unroll
    for (int q = 0; q < 4; ++q) {
        #pragma unroll
        for (int t = 0; t < 2; ++t) {
            acc[q][t][0] = 0.f; acc[q][t][1] = 0.f; acc[q][t][2] = 0.f; acc[q][t][3] = 0.f;
        }
    }

    // ---- K-loop: 4 chunks x 8 rows, double-buffered W staging ----
    int buf = 0;
    #pragma unroll 1
    for (int c = 0; c < 4; ++c) {
        // issue next chunk's global loads (write to LDS after compute)
        if (c < 3) {
            const float* p = w2 + ((c + 1) * 8 + jr) * 1024 + tt * 4;
            #pragma unroll
            for (int i = 0; i < 8; ++i)
                stg[i] = *reinterpret_cast<const f32x4*>(p + i * 128);
        } else if (tid < 32) {             // bias2 row (jr==0, tt==tid)
            const float* p = b2 + tt * 4;
            #pragma unroll
            for (int i = 0; i < 8; ++i)
                stg[i] = *reinterpret_cast<const f32x4*>(p + i * 128);
        }

        const ushort* Wb = &WL[buf * 8192];
        #pragma unroll
        for (int j8 = 0; j8 < 8; ++j8) {
            const int kk = c * 8 + j8;
            bf16x8 bf0 = *reinterpret_cast<const bf16x8*>(&Wb[j8 * 1024 + lg * 256 + l15 * 8]);
            bf16x8 bf1 = *reinterpret_cast<const bf16x8*>(&Wb[j8 * 1024 + lg * 256 + (16 + l15) * 8]);
            #pragma unroll
            for (int q = 0; q < 4; ++q) {
                const float hv = bf2f(hT[kk * BM + wid * 64 + q * 16 + l15]);
                bf16x8 af;
                #pragma unroll
                for (int i = 0; i < 8; ++i)
                    af[i] = (short)f2bf(hv * tmpf[q][i]);
                acc[q][0] = __builtin_amdgcn_mfma_f32_16x16x32_bf16(af, bf0, acc[q][0], 0, 0, 0);
                acc[q][1] = __builtin_amdgcn_mfma_f32_16x16x32_bf16(af, bf1, acc[q][1], 0, 0, 0);
            }
        }

        if (c < 3) write_stage(buf ^ 1);
        else if (tid < 32) write_stage(buf ^ 1);
        __syncthreads();
        buf ^= 1;
    }

    // ---- bias2 K-step (implicit h == 1, A = bf16(tmp)) ----
    {
        bf16x8 bb0 = *reinterpret_cast<const bf16x8*>(&WL[buf * 8192 + lg * 256 + l15 * 8]);
        bf16x8 bb1 = *reinterpret_cast<const bf16x8*>(&WL[buf * 8192 + lg * 256 + (16 + l15) * 8]);
        #pragma unroll
        for (int q = 0; q < 4; ++q) {
            bf16x8 af;
            #pragma unroll
            for (int i = 0; i < 8; ++i)
                af[i] = (short)f2bf(tmpf[q][i]);
            acc[q][0] = __builtin_amdgcn_mfma_f32_16x16x32_bf16(af, bb0, acc[q][0], 0, 0, 0);
            acc[q][1] = __builtin_amdgcn_mfma_f32_16x16x32_bf16(af, bb1, acc[q][1], 0, 0, 0);
        }
    }

    // ---- epilogue: out[e,m2,d2] = sum_k2 C[e, m2*4+k2] * basis2[e,k2,d2] ----
    // C layout (verified): col a = lane&15 (+16*t), row = (lane>>4)*4 + reg.
    const int k2  = lane & 3;
    const int m2l = (lane >> 2) & 3;
    #pragma unroll
    for (int q = 0; q < 4; ++q) {
        #pragma unroll
        for (int r = 0; r < 4; ++r) {
            const int eg = base + wid * 64 + q * 16 + lg * 4 + r;
            f32x4 bs2 = *reinterpret_cast<const f32x4*>(basis2 + eg * 16 + k2 * 4);
            #pragma unroll
            for (int t = 0; t < 2; ++t) {
                const float v = acc[q][t][r];
                float p0 = v * bs2[0], p1 = v * bs2[1], p2 = v * bs2[2], p3 = v * bs2[3];
                p0 += __shfl_xor(p0, 1); p0 += __shfl_xor(p0, 2);
                p1 += __shfl_xor(p1, 1); p1 += __shfl_xor(p1, 2);
                p2 += __shfl_xor(p2, 1); p2 += __shfl_xor(p2, 2);
                p3 += __shfl_xor(p3, 1); p3 += __shfl_xor(p3, 2);
                const float ov = (k2 == 0) ? p0 : (k2 == 1) ? p1 : (k2 == 2) ? p2 : p3;
                out[eg * 32 + (t * 4 + m2l) * 4 + k2] = ov;
            }
        }
    }
}

extern "C" void kernel_launch(void* const* d_in, const int* in_sizes, int n_in,
                              void* d_out, int out_size, void* d_ws, size_t ws_size,
                              hipStream_t stream) {
    const float* basis1 = (const float*)d_in[0];
    const float* basis2 = (const float*)d_in[1];
    const float* ef     = (const float*)d_in[2];
    const float* f      = (const float*)d_in[3];
    const int*   src    = (const int*)  d_in[4];
    const float* w1     = (const float*)d_in[5];
    const float* b1     = (const float*)d_in[6];
    const float* w2     = (const float*)d_in[7];
    const float* b2     = (const float*)d_in[8];
    float* out = (float*)d_out;

    const int E = in_sizes[4];            // 262144
    const int nblocks = E / BM;           // 1024

    equiv_conv_mfma<<<nblocks, TPB, 0, stream>>>(
        basis1, basis2, ef, f, src, w1, b1, w2, b2, out);
}

// Round 5
// 57.886 us; speedup vs baseline: 19.5033x; 1.0996x over previous
//
#include <hip/hip_runtime.h>
#include <hip/hip_bf16.h>

// EquivariantConvolution via bf16 MFMA — R4: exact R1 structure (passed, 63.7us)
// with ONE change: WL double-buffer (32KB) -> single buffer (16KB).
// LDS 64KB -> 48KB => 3 blocks/CU (was 2). All index math identical to R1.
// GEMM view: C[e,a] = sum_{j,b} (h[e,j]*tmp[e,b]) * w2[j, a*32+b], K=1056 incl bias row, N=32.

#define TPB 256
#define BM  256

typedef __attribute__((ext_vector_type(8))) short bf16x8;
typedef __attribute__((ext_vector_type(4))) float f32x4;

__device__ __forceinline__ ushort f2bf(float x) {
    __hip_bfloat16 b = __float2bfloat16(x);
    return __builtin_bit_cast(ushort, b);
}
__device__ __forceinline__ float bf2f(ushort u) {
    unsigned int v = ((unsigned int)u) << 16;
    return __builtin_bit_cast(float, v);
}

__global__ __launch_bounds__(TPB, 3) void equiv_conv_mfma(
    const float* __restrict__ basis1,
    const float* __restrict__ basis2,
    const float* __restrict__ ef,
    const float* __restrict__ f,
    const int*   __restrict__ src_idx,
    const float* __restrict__ w1,
    const float* __restrict__ b1,
    const float* __restrict__ w2,
    const float* __restrict__ b2,
    float* __restrict__ out)
{
    // LDS: 16 KB + 16 KB + 16 KB = 48 KB -> 3 blocks/CU.
    __shared__ ushort hT[32 * BM];        // [j][edge]  bf16 bits
    __shared__ ushort tmpT[4 * BM * 8];   // [g][edge][8] bf16 (b = g*8+i)
    __shared__ ushort WL[8192];           // [jr][g][a][i] bf16 (8 rows/chunk, single buffer)

    const int tid  = threadIdx.x;
    const int base = blockIdx.x * BM;
    const int e    = base + tid;

    const int jr = tid >> 5;      // row-in-chunk this thread stages
    const int tt = tid & 31;

    // ---- issue chunk-0 w2 loads early (land under prologue compute) ----
    f32x4 stg[8];
    {
        const float* p = w2 + jr * 1024 + tt * 4;
        #pragma unroll
        for (int i = 0; i < 8; ++i)
            stg[i] = *reinterpret_cast<const f32x4*>(p + i * 128);
    }

    // write staged regs (bf16) into WL; works for bias row too (jr==0).
    auto write_stage = [&]() {
        const int g   = (tt >> 1) & 3;
        const int i0v = (tt & 1) * 4;
        #pragma unroll
        for (int i = 0; i < 8; ++i) {
            const int a = i * 4 + (tt >> 3);
            unsigned int lo = (unsigned int)f2bf(stg[i][0]) | ((unsigned int)f2bf(stg[i][1]) << 16);
            unsigned int hi = (unsigned int)f2bf(stg[i][2]) | ((unsigned int)f2bf(stg[i][3]) << 16);
            *reinterpret_cast<uint2*>(&WL[jr * 1024 + g * 256 + a * 8 + i0v]) =
                make_uint2(lo, hi);
        }
    };

    // ---- prologue: h = relu(ef@w1 + b1) -> hT (bf16) ----
    {
        float efr[16];
        const f32x4* p4 = reinterpret_cast<const f32x4*>(ef + e * 16);
        #pragma unroll
        for (int i = 0; i < 4; ++i) {
            f32x4 v = p4[i];
            efr[i*4+0] = v[0]; efr[i*4+1] = v[1]; efr[i*4+2] = v[2]; efr[i*4+3] = v[3];
        }
        #pragma unroll
        for (int j = 0; j < 32; ++j) {
            float hv = b1[j];
            #pragma unroll
            for (int i = 0; i < 16; ++i)
                hv = fmaf(efr[i], w1[i * 32 + j], hv);
            hT[j * BM + tid] = f2bf(fmaxf(hv, 0.f));
        }
    }

    // ---- prologue: tmp[m*4+k] = sum_d f_src[m][d]*basis1[d][k] -> tmpT (bf16) ----
    {
        float fr[32];
        const int s = src_idx[e];
        const f32x4* p4 = reinterpret_cast<const f32x4*>(f + s * 32);
        #pragma unroll
        for (int i = 0; i < 8; ++i) {
            f32x4 v = p4[i];
            fr[i*4+0] = v[0]; fr[i*4+1] = v[1]; fr[i*4+2] = v[2]; fr[i*4+3] = v[3];
        }
        float bs1[16];
        const f32x4* q4 = reinterpret_cast<const f32x4*>(basis1 + e * 16);
        #pragma unroll
        for (int i = 0; i < 4; ++i) {
            f32x4 v = q4[i];
            bs1[i*4+0] = v[0]; bs1[i*4+1] = v[1]; bs1[i*4+2] = v[2]; bs1[i*4+3] = v[3];
        }
        float tmp[32];
        #pragma unroll
        for (int m = 0; m < 8; ++m) {
            #pragma unroll
            for (int k = 0; k < 4; ++k) {
                float v = 0.f;
                #pragma unroll
                for (int d = 0; d < 4; ++d)
                    v = fmaf(fr[m*4+d], bs1[d*4+k], v);
                tmp[m*4+k] = v;
            }
        }
        #pragma unroll
        for (int g = 0; g < 4; ++g) {
            uint4 pk;
            pk.x = (unsigned int)f2bf(tmp[g*8+0]) | ((unsigned int)f2bf(tmp[g*8+1]) << 16);
            pk.y = (unsigned int)f2bf(tmp[g*8+2]) | ((unsigned int)f2bf(tmp[g*8+3]) << 16);
            pk.z = (unsigned int)f2bf(tmp[g*8+4]) | ((unsigned int)f2bf(tmp[g*8+5]) << 16);
            pk.w = (unsigned int)f2bf(tmp[g*8+6]) | ((unsigned int)f2bf(tmp[g*8+7]) << 16);
            *reinterpret_cast<uint4*>(&tmpT[(g * BM + tid) * 8]) = pk;
        }
    }

    // chunk 0 -> WL
    write_stage();
    __syncthreads();

    // ---- per-wave tile setup ----
    const int lane = tid & 63;
    const int wid  = tid >> 6;
    const int l15  = lane & 15;
    const int lg   = lane >> 4;            // K-group (b = lg*8 + i)

    float tmpf[4][8];                      // per-tile tmp[b] as f32, K-loop invariant
    #pragma unroll
    for (int q = 0; q < 4; ++q) {
        const int edge = wid * 64 + q * 16 + l15;
        bf16x8 tv = *reinterpret_cast<const bf16x8*>(&tmpT[(lg * BM + edge) * 8]);
        #pragma unroll
        for (int i = 0; i < 8; ++i) tmpf[q][i] = bf2f((ushort)tv[i]);
    }

    f32x4 acc[4][2];
    #pragma unroll
    for (int q = 0; q < 4; ++q) {
        #pragma unroll
        for (int t = 0; t < 2; ++t) {
            acc[q][t][0] = 0.f; acc[q][t][1] = 0.f; acc[q][t][2] = 0.f; acc[q][t][3] = 0.f;
        }
    }

    // ---- K-loop: 4 chunks x 8 rows, single-buffered WL ----
    #pragma unroll 1
    for (int c = 0; c < 4; ++c) {
        // issue next chunk's global loads (write to LDS after compute + barrier)
        if (c < 3) {
            const float* p = w2 + ((c + 1) * 8 + jr) * 1024 + tt * 4;
            #pragma unroll
            for (int i = 0; i < 8; ++i)
                stg[i] = *reinterpret_cast<const f32x4*>(p + i * 128);
        } else if (tid < 32) {             // bias2 row (jr==0, tt==tid)
            const float* p = b2 + tt * 4;
            #pragma unroll
            for (int i = 0; i < 8; ++i)
                stg[i] = *reinterpret_cast<const f32x4*>(p + i * 128);
        }

        const ushort* Wb = WL;
        #pragma unroll
        for (int j8 = 0; j8 < 8; ++j8) {
            const int kk = c * 8 + j8;
            bf16x8 bf0 = *reinterpret_cast<const bf16x8*>(&Wb[j8 * 1024 + lg * 256 + l15 * 8]);
            bf16x8 bf1 = *reinterpret_cast<const bf16x8*>(&Wb[j8 * 1024 + lg * 256 + (16 + l15) * 8]);
            #pragma unroll
            for (int q = 0; q < 4; ++q) {
                const float hv = bf2f(hT[kk * BM + wid * 64 + q * 16 + l15]);
                bf16x8 af;
                #pragma unroll
                for (int i = 0; i < 8; ++i)
                    af[i] = (short)f2bf(hv * tmpf[q][i]);
                acc[q][0] = __builtin_amdgcn_mfma_f32_16x16x32_bf16(af, bf0, acc[q][0], 0, 0, 0);
                acc[q][1] = __builtin_amdgcn_mfma_f32_16x16x32_bf16(af, bf1, acc[q][1], 0, 0, 0);
            }
        }

        __syncthreads();                   // everyone done reading WL
        if (c < 3) write_stage();
        else if (tid < 32) write_stage();  // bias row into row 0
        __syncthreads();                   // WL ready for next chunk / bias step
    }

    // ---- bias2 K-step (implicit h == 1, A = bf16(tmp)) ----
    {
        bf16x8 bb0 = *reinterpret_cast<const bf16x8*>(&WL[lg * 256 + l15 * 8]);
        bf16x8 bb1 = *reinterpret_cast<const bf16x8*>(&WL[lg * 256 + (16 + l15) * 8]);
        #pragma unroll
        for (int q = 0; q < 4; ++q) {
            bf16x8 af;
            #pragma unroll
            for (int i = 0; i < 8; ++i)
                af[i] = (short)f2bf(tmpf[q][i]);
            acc[q][0] = __builtin_amdgcn_mfma_f32_16x16x32_bf16(af, bb0, acc[q][0], 0, 0, 0);
            acc[q][1] = __builtin_amdgcn_mfma_f32_16x16x32_bf16(af, bb1, acc[q][1], 0, 0, 0);
        }
    }

    // ---- epilogue: out[e,m2,d2] = sum_k2 C[e, m2*4+k2] * basis2[e,k2,d2] ----
    // C layout (verified): col a = lane&15 (+16*t), row = (lane>>4)*4 + reg.
    const int k2  = lane & 3;
    const int m2l = (lane >> 2) & 3;
    #pragma unroll
    for (int q = 0; q < 4; ++q) {
        #pragma unroll
        for (int r = 0; r < 4; ++r) {
            const int eg = base + wid * 64 + q * 16 + lg * 4 + r;
            f32x4 bs2 = *reinterpret_cast<const f32x4*>(basis2 + eg * 16 + k2 * 4);
            #pragma unroll
            for (int t = 0; t < 2; ++t) {
                const float v = acc[q][t][r];
                float p0 = v * bs2[0], p1 = v * bs2[1], p2 = v * bs2[2], p3 = v * bs2[3];
                p0 += __shfl_xor(p0, 1); p0 += __shfl_xor(p0, 2);
                p1 += __shfl_xor(p1, 1); p1 += __shfl_xor(p1, 2);
                p2 += __shfl_xor(p2, 1); p2 += __shfl_xor(p2, 2);
                p3 += __shfl_xor(p3, 1); p3 += __shfl_xor(p3, 2);
                const float ov = (k2 == 0) ? p0 : (k2 == 1) ? p1 : (k2 == 2) ? p2 : p3;
                out[eg * 32 + (t * 4 + m2l) * 4 + k2] = ov;
            }
        }
    }
}

extern "C" void kernel_launch(void* const* d_in, const int* in_sizes, int n_in,
                              void* d_out, int out_size, void* d_ws, size_t ws_size,
                              hipStream_t stream) {
    const float* basis1 = (const float*)d_in[0];
    const float* basis2 = (const float*)d_in[1];
    const float* ef     = (const float*)d_in[2];
    const float* f      = (const float*)d_in[3];
    const int*   src    = (const int*)  d_in[4];
    const float* w1     = (const float*)d_in[5];
    const float* b1     = (const float*)d_in[6];
    const float* w2     = (const float*)d_in[7];
    const float* b2     = (const float*)d_in[8];
    float* out = (float*)d_out;

    const int E = in_sizes[4];            // 262144
    const int nblocks = E / BM;           // 1024

    equiv_conv_mfma<<<nblocks, TPB, 0, stream>>>(
        basis1, basis2, ef, f, src, w1, b1, w2, b2, out);
}